// Round 5
// baseline (246.409 us; speedup 1.0000x reference)
//
#include <hip/hip_runtime.h>

// SPGG Q-learning step on a 2048x2048 torus — bit-parallel fused kernel.
//
// Round-4 post-mortem: LDS port (~52 ds_read/thread ~= 30us) + VALU (~490
// instr/thread ~= 26us) dominate; barrier removal changed nothing. This
// version deletes LDS entirely and cuts VALU ~40%:
//   * __ballot converts a wave's 64-column tt row into one 64-bit SGPR mask
//     (7 rows + 1 ballot for all halos). Per-lane 7-bit windows = 2 shifts.
//   * SWAR: windows spread to nibbles; one 32-bit add chain computes ALL
//     coop_num values of a row at once (values <=5, no nibble carry).
//   * profit is a pure function of (cn_c,cn_u,cn_d,cn_l,cn_r,c_cc) -> 16-bit
//     code; a prologue kernel fills a 64K-entry f32 LUT in d_ws with the
//     BIT-EXACT reference FP chain; main kernel does 2 cached lookups.
// upd recomputed for the selected neighbor bit-identically (as rounds 3-4).
// exp in double, rounded once. Numerics identical to all passing rounds.

#define LSIDE 2048
#define LMASK 2047
#define LSHIFT 11
#define NCELL (LSIDE * LSIDE)

__global__ __launch_bounds__(256) void spgg_lut_init(float* __restrict__ lut) {
    int idx = blockIdx.x * 256 + threadIdx.x;      // 0..65535
    int cn_c = idx & 7;
    int cn_u = (idx >> 3) & 7;
    int cn_d = (idx >> 6) & 7;
    int cn_l = (idx >> 9) & 7;
    int cn_r = (idx >> 12) & 7;
    int ccc  = (idx >> 15) & 1;
    const float KB = 0.5554f;   // float32(R / 5.0)
    float b_c = __fmul_rn((float)cn_c, KB);
    float b_u = __fmul_rn((float)cn_u, KB);
    float b_d = __fmul_rn((float)cn_d, KB);
    float b_l = __fmul_rn((float)cn_l, KB);
    float b_r = __fmul_rn((float)cn_r, KB);
    float s0 = __fadd_rn(__fadd_rn(__fadd_rn(__fadd_rn(b_c, b_u), b_d), b_l), b_r);
    float s1 = __fadd_rn(__fadd_rn(__fadd_rn(__fadd_rn(
                   __fsub_rn(b_c, 1.0f), __fsub_rn(b_u, 1.0f)),
                   __fsub_rn(b_d, 1.0f)), __fsub_rn(b_l, 1.0f)),
                   __fsub_rn(b_r, 1.0f));
    lut[idx] = ccc ? s1 : s0;
}

__global__ __launch_bounds__(256) void spgg_fused(
    const int* __restrict__ tmin,
    const int* __restrict__ tt,
    const float* __restrict__ Q,
    const int* __restrict__ ldir,
    const float* __restrict__ lp,
    const float* __restrict__ lut,
    float* __restrict__ Qn,
    float* __restrict__ prof,
    float* __restrict__ t1out)
{
    const int tid = threadIdx.x;
    const int l   = tid & 63;
    const int idx = blockIdx.x * 256 + tid;
    const int i   = idx >> LSHIFT;
    const int j   = idx & LMASK;
    const int j0w = j & ~63;         // wave column base

    // ---- coalesced per-cell loads, issued early ----
    float4 qr  = ((const float4*)Q)[idx];
    int    A   = tmin[idx];
    int    dir = ldir[idx];
    float  pv  = lp[idx];

    // ---- halo ballot: 42 cells (7 rows x [3 left + 3 right]) in one mask ----
    unsigned long long hm;
    {
        int hv = 0;
        int o  = l % 6;
        int hr = l / 6;
        if (l < 42) {
            int col = (j0w + ((o < 3) ? (o - 3) : (o + 61))) & LMASK;
            int row = (i + hr - 3) & LMASK;
            hv = tt[(row << LSHIFT) + col];
        }
        hm = __ballot(l < 42 && hv == 1);
    }

    // ---- 7 row masks via ballot; per-lane 7-bit windows; nibble spread ----
    unsigned int E[7];
#pragma unroll
    for (int r = 0; r < 7; ++r) {
        int row = (i + r - 3) & LMASK;
        int v = tt[(row << LSHIFT) + j0w + l];
        unsigned long long mm = __ballot(v == 1);
        unsigned int h6 = (unsigned int)((hm >> (6 * r)) & 63ull);
        unsigned long long lo = (mm << 3) | (unsigned long long)(h6 & 7u);
        unsigned long long hi = (mm >> 29) | ((unsigned long long)(h6 >> 3) << 35);
        unsigned int win = (unsigned int)(((l < 58) ? (lo >> l) : (hi >> (l - 32))) & 0x7Full);
        // spread 7 bits to 7 nibbles: bit k -> bit 4k
        unsigned int x = win;
        x = (x | (x << 12)) & 0x0007000Fu;
        x = (x | (x << 6))  & 0x03030303u;
        x = (x | (x << 3))  & 0x11111111u;
        E[r] = x;
    }

    // ---- SWAR coop_num: C[r] nibble c = cn at (row i+r-2, col j+c-3) ----
    unsigned int C[5];
#pragma unroll
    for (int r = 0; r < 5; ++r) {
        unsigned int e = E[r + 1];
        C[r] = E[r] + e + E[r + 2] + (e << 4) + (e >> 4);
    }

    // ---- own-cell profit via LUT ----
    unsigned int cn_c = (C[2] >> 12) & 7u;
    unsigned int cn_u = (C[1] >> 12) & 7u;
    unsigned int cn_d = (C[3] >> 12) & 7u;
    unsigned int cn_l = (C[2] >> 8)  & 7u;
    unsigned int cn_r = (C[2] >> 16) & 7u;
    unsigned int mcc  = (E[3] >> 12) & 1u;
    unsigned int io   = cn_c | (cn_u << 3) | (cn_d << 6) | (cn_l << 9)
                      | (cn_r << 12) | (mcc << 15);
    float p_own = lut[io];

    // ---- neighbor cell (dir: 0=left 1=right 2=up 3=down) ----
    int di = (dir == 3) - (dir == 2);
    int dj = (dir == 1) - (dir == 0);
    int nidx = (((i + di) & LMASK) << LSHIFT) + ((j + dj) & LMASK);
    float4 qn4 = ((const float4*)Q)[nidx];
    int    An  = tmin[nidx];

    // row-relative selects: lattice row offset d maps to C[d+2] / E[d+3]
    unsigned int Ca = (di < 0) ? C[0] : ((di > 0) ? C[2] : C[1]);  // row di-1
    unsigned int Cb = (di < 0) ? C[1] : ((di > 0) ? C[3] : C[2]);  // row di
    unsigned int Cc = (di < 0) ? C[2] : ((di > 0) ? C[4] : C[3]);  // row di+1
    unsigned int Eb = (di < 0) ? E[2] : ((di > 0) ? E[4] : E[3]);  // row di
    int sh = 4 * dj + 12;                 // nibble shift for column dj+3
    unsigned int cnc_n = (Cb >> sh) & 7u;
    unsigned int cnu_n = (Ca >> sh) & 7u;
    unsigned int cnd_n = (Cc >> sh) & 7u;
    unsigned int cnl_n = (Cb >> (sh - 4)) & 7u;
    unsigned int cnr_n = (Cb >> (sh + 4)) & 7u;
    unsigned int mnb   = (Eb >> sh) & 1u;
    unsigned int in_   = cnc_n | (cnu_n << 3) | (cnd_n << 6) | (cnl_n << 9)
                       | (cnr_n << 12) | (mnb << 15);
    float p_nb = lut[in_];

    // ---- Q updates (bit-exact reference op order) ----
    const float ETA       = 0.8f;
    const float ONE_M_ETA = 0.2f;
    const float GAMMA     = 0.8f;
    int B  = (int)mcc;    // tt values are 0/1
    int Bn = (int)mnb;

    float q0 = (B == 0) ? qr.x : qr.z;
    float q1 = (B == 0) ? qr.y : qr.w;
    float mx = fmaxf(q0, q1);
    int k = A * 2 + B;
    float old = (k == 0) ? qr.x : ((k == 1) ? qr.y : ((k == 2) ? qr.z : qr.w));
    float upd = __fadd_rn(__fmul_rn(ONE_M_ETA, old),
                          __fmul_rn(ETA, __fadd_rn(p_own, __fmul_rn(GAMMA, mx))));

    float nq0 = (Bn == 0) ? qn4.x : qn4.z;
    float nq1 = (Bn == 0) ? qn4.y : qn4.w;
    float nmx = fmaxf(nq0, nq1);
    int kn = An * 2 + Bn;
    float nold = (kn == 0) ? qn4.x : ((kn == 1) ? qn4.y : ((kn == 2) ? qn4.z : qn4.w));
    float upd_nb = __fadd_rn(__fmul_rn(ONE_M_ETA, nold),
                             __fmul_rn(ETA, __fadd_rn(p_nb, __fmul_rn(GAMMA, nmx))));

    float4 qo;
    qo.x = (k == 0) ? upd : qr.x;
    qo.y = (k == 1) ? upd : qr.y;
    qo.z = (k == 2) ? upd : qr.z;
    qo.w = (k == 3) ? upd : qr.w;
    ((float4*)Qn)[idx] = qo;
    prof[idx] = p_own;

    // ---- fermi decision ----
    float e1 = __fsub_rn(upd, upd_nb);
    float e2 = __fmul_rn(e1, 2.0f);          // / K_FERMI(0.5) exactly
    float ex = (float)exp((double)e2);       // correctly-rounded f32 exp
    float W  = __fdiv_rn(1.0f, __fadd_rn(1.0f, ex));
    int sel = (pv <= W) ? Bn : B;
    t1out[idx] = (float)sel;
}

extern "C" void kernel_launch(void* const* d_in, const int* in_sizes, int n_in,
                              void* d_out, int out_size, void* d_ws, size_t ws_size,
                              hipStream_t stream) {
    const int*   type_t_minus = (const int*)d_in[0];
    const int*   type_t       = (const int*)d_in[1];
    const float* Q_tensor     = (const float*)d_in[2];
    const int*   ldir         = (const int*)d_in[3];
    const float* lprob        = (const float*)d_in[4];

    float* out   = (float*)d_out;
    float* Qn    = out;                       // [N*4]
    float* t1out = out + (size_t)4 * NCELL;   // [N]
    float* prof  = out + (size_t)5 * NCELL;   // [N]
    float* lut   = (float*)d_ws;              // 65536 floats (256 KB)

    spgg_lut_init<<<256, 256, 0, stream>>>(lut);
    spgg_fused<<<NCELL / 256, 256, 0, stream>>>(type_t_minus, type_t, Q_tensor,
                                                ldir, lprob, lut,
                                                Qn, prof, t1out);
}

// Round 6
// 224.102 us; speedup vs baseline: 1.0995x; 1.0995x over previous
//
#include <hip/hip_runtime.h>

// SPGG Q-learning step on a 2048x2048 torus — bit-parallel fused kernel,
// 4 rows per wave, no LDS, no LUT.
//
// Round-5 post-mortem: the 256KB profit LUT's per-lane-divergent gathers sat
// on the critical chain (L2 latency, L1-uncacheable) and regressed 75->100us.
// Round-4's LDS path cost ~32us of LDS-port time. This version keeps the
// validated ballot/SWAR cn machinery (bit-identical ints), computes profit
// DIRECTLY from cn values (~25 f32 ops, no memory), and amortizes the mask
// machinery 4x: each wave handles 4 rows x 64 cols using 10 row ballots +
// 1 halo ballot + 8 SWAR C-words.
//
//   * __ballot turns a 64-col tt row into a 64-bit mask (SGPR).
//   * nibble-spread E[r]; C[m] = E[m]+E[m+1]+E[m+2]+(E[m+1]<<4)+(E[m+1]>>4)
//     gives ALL coop_num of a row in one word (values <=5, no carry).
//   * upd recomputed for the selected neighbor bit-identically.
//   * exp in double, rounded once (identical to all passing rounds).

#define LSIDE 2048
#define LMASK 2047
#define LSHIFT 11
#define NCELL (LSIDE * LSIDE)

__global__ __launch_bounds__(256) void spgg_fused(
    const int* __restrict__ tmin,
    const int* __restrict__ tt,
    const float* __restrict__ Q,
    const int* __restrict__ ldir,
    const float* __restrict__ lp,
    float* __restrict__ Qn,
    float* __restrict__ prof,
    float* __restrict__ t1out)
{
    const int tid = threadIdx.x;
    const int w   = tid >> 6;            // wave in block
    const int l   = tid & 63;            // lane
    const int bx  = blockIdx.x;
    const int tile_i = bx >> 5;          // 128 bands of 16 rows
    const int tile_j = bx & 31;          // 32 col-tiles of 64
    const int r0  = (tile_i << 4) + (w << 2);   // wave's first row (0..2044)
    const int j0w = tile_j << 6;
    const int j   = j0w + l;

    // ---- halo ballot: 10 rows x 6 halo cols (3 left, 3 right) in one mask ----
    unsigned long long hm;
    {
        int hv = 0;
        if (l < 60) {
            int o  = l % 6;
            int hr = l / 6;
            int col = (j0w + ((o < 3) ? (o - 3) : (o + 61))) & LMASK;
            int row = (r0 + hr - 3) & LMASK;
            hv = tt[(row << LSHIFT) + col];
        }
        hm = __ballot(l < 60 && hv == 1);
    }

    // ---- 10 row masks -> per-lane 7-bit windows -> nibble-spread E ----
    unsigned int E[10];
#pragma unroll
    for (int r = 0; r < 10; ++r) {
        int row = (r0 + r - 3) & LMASK;
        int v = tt[(row << LSHIFT) + j];
        unsigned long long mm = __ballot(v == 1);
        unsigned int h6 = (unsigned int)((hm >> (6 * r)) & 63ull);
        unsigned long long lo = (mm << 3) | (unsigned long long)(h6 & 7u);
        unsigned long long hi = (mm >> 29) | ((unsigned long long)(h6 >> 3) << 35);
        unsigned int win = (unsigned int)(((l < 58) ? (lo >> l) : (hi >> (l - 32))) & 0x7Full);
        unsigned int x = win;                   // spread bit k -> bit 4k
        x = (x | (x << 12)) & 0x0007000Fu;
        x = (x | (x << 6))  & 0x03030303u;
        x = (x | (x << 3))  & 0x11111111u;
        E[r] = x;
    }

    // ---- SWAR coop_num rows: C[m] = cn at lattice row r0+m-2 ----
    unsigned int C[8];
#pragma unroll
    for (int m = 0; m < 8; ++m) {
        unsigned int e = E[m + 1];
        C[m] = E[m] + e + E[m + 2] + (e << 4) + (e >> 4);
    }

    const float KB        = 0.5554f;  // float32(R / 5.0)
    const float ETA       = 0.8f;
    const float ONE_M_ETA = 0.2f;     // float32(1.0 - 0.8)
    const float GAMMA     = 0.8f;

    // profit from cn values — exact reference op order.
    auto profit_of = [&](unsigned int cc, unsigned int cu, unsigned int cd,
                         unsigned int cl, unsigned int cr, unsigned int m) -> float {
        float b_c = __fmul_rn((float)cc, KB);
        float b_u = __fmul_rn((float)cu, KB);
        float b_d = __fmul_rn((float)cd, KB);
        float b_l = __fmul_rn((float)cl, KB);
        float b_r = __fmul_rn((float)cr, KB);
        float s0 = __fadd_rn(__fadd_rn(__fadd_rn(__fadd_rn(b_c, b_u), b_d), b_l), b_r);
        float s1 = __fadd_rn(__fadd_rn(__fadd_rn(__fadd_rn(
                       __fsub_rn(b_c, 1.0f), __fsub_rn(b_u, 1.0f)),
                       __fsub_rn(b_d, 1.0f)), __fsub_rn(b_l, 1.0f)),
                       __fsub_rn(b_r, 1.0f));
        return m ? s1 : s0;
    };

    auto upd_of = [&](float p, float4 q4, int Ax, int Bx, int kx) -> float {
        float q0 = (Bx == 0) ? q4.x : q4.z;
        float q1 = (Bx == 0) ? q4.y : q4.w;
        float mx = fmaxf(q0, q1);
        float old = (kx == 0) ? q4.x : ((kx == 1) ? q4.y : ((kx == 2) ? q4.z : q4.w));
        return __fadd_rn(__fmul_rn(ONE_M_ETA, old),
                         __fmul_rn(ETA, __fadd_rn(p, __fmul_rn(GAMMA, mx))));
    };

#pragma unroll
    for (int t = 0; t < 4; ++t) {
        const int row = r0 + t;                   // no wrap (r0+3 <= 2047)
        const int idx = (row << LSHIFT) + j;

        // coalesced own-cell loads
        float4 qr  = ((const float4*)Q)[idx];
        int    A   = tmin[idx];
        int    dir = ldir[idx];
        float  pv  = lp[idx];

        // neighbor (dir: 0=left 1=right 2=up 3=down) — divergent gathers
        int di = (dir == 3) - (dir == 2);
        int dj = (dir == 1) - (dir == 0);
        int nidx = (((row + di) & LMASK) << LSHIFT) + ((j + dj) & LMASK);
        float4 qn4 = ((const float4*)Q)[nidx];
        int    An  = tmin[nidx];

        // own-cell cn extraction (center col = nibble 3 -> shift 12)
        unsigned int cn_c = (C[t + 2] >> 12) & 7u;
        unsigned int cn_u = (C[t + 1] >> 12) & 7u;
        unsigned int cn_d = (C[t + 3] >> 12) & 7u;
        unsigned int cn_l = (C[t + 2] >> 8)  & 7u;
        unsigned int cn_r = (C[t + 2] >> 16) & 7u;
        unsigned int mcc  = (E[t + 3] >> 12) & 1u;
        float p_own = profit_of(cn_c, cn_u, cn_d, cn_l, cn_r, mcc);

        // neighbor cn: row-select by di, column shift by dj
        unsigned int Ca = (di < 0) ? C[t]     : ((di > 0) ? C[t + 2] : C[t + 1]);
        unsigned int Cb = (di < 0) ? C[t + 1] : ((di > 0) ? C[t + 3] : C[t + 2]);
        unsigned int Cc = (di < 0) ? C[t + 2] : ((di > 0) ? C[t + 4] : C[t + 3]);
        unsigned int Eb = (di < 0) ? E[t + 2] : ((di > 0) ? E[t + 4] : E[t + 3]);
        int sh = 4 * dj + 12;
        unsigned int cnc_n = (Cb >> sh) & 7u;
        unsigned int cnu_n = (Ca >> sh) & 7u;
        unsigned int cnd_n = (Cc >> sh) & 7u;
        unsigned int cnl_n = (Cb >> (sh - 4)) & 7u;
        unsigned int cnr_n = (Cb >> (sh + 4)) & 7u;
        unsigned int mnb   = (Eb >> sh) & 1u;
        float p_nb = profit_of(cnc_n, cnu_n, cnd_n, cnl_n, cnr_n, mnb);

        // Q updates (bit-exact reference op order)
        int B  = (int)mcc;
        int Bn = (int)mnb;
        int k  = A * 2 + B;
        int kn = An * 2 + Bn;
        float upd    = upd_of(p_own, qr,  A,  B,  k);
        float upd_nb = upd_of(p_nb,  qn4, An, Bn, kn);

        float4 qo;
        qo.x = (k == 0) ? upd : qr.x;
        qo.y = (k == 1) ? upd : qr.y;
        qo.z = (k == 2) ? upd : qr.z;
        qo.w = (k == 3) ? upd : qr.w;
        ((float4*)Qn)[idx] = qo;
        prof[idx] = p_own;

        // fermi decision
        float e1 = __fsub_rn(upd, upd_nb);
        float e2 = __fmul_rn(e1, 2.0f);          // / K_FERMI(0.5) exactly
        float ex = (float)exp((double)e2);       // correctly-rounded f32 exp
        float W  = __fdiv_rn(1.0f, __fadd_rn(1.0f, ex));
        int sel = (pv <= W) ? Bn : B;
        t1out[idx] = (float)sel;
    }
}

extern "C" void kernel_launch(void* const* d_in, const int* in_sizes, int n_in,
                              void* d_out, int out_size, void* d_ws, size_t ws_size,
                              hipStream_t stream) {
    const int*   type_t_minus = (const int*)d_in[0];
    const int*   type_t       = (const int*)d_in[1];
    const float* Q_tensor     = (const float*)d_in[2];
    const int*   ldir         = (const int*)d_in[3];
    const float* lprob        = (const float*)d_in[4];

    float* out   = (float*)d_out;
    float* Qn    = out;                       // [N*4]
    float* t1out = out + (size_t)4 * NCELL;   // [N]
    float* prof  = out + (size_t)5 * NCELL;   // [N]

    const int threads = 256;                  // 4 waves; each does 4 rows x 64 cols
    const int blocks  = NCELL / (threads * 4);  // 4096
    spgg_fused<<<blocks, threads, 0, stream>>>(type_t_minus, type_t, Q_tensor,
                                               ldir, lprob, Qn, prof, t1out);
}